// Round 1
// 296.755 us; speedup vs baseline: 1.1047x; 1.1047x over previous
//
#include <hip/hip_runtime.h>

#define NN 50000
#define NE 800000
#define NH 64
#define NG 500
#define NPAD 50176   // 196*256
#define NBKT 782     // ceil(NN/64) 64-node buckets
#define CAP 1536     // padded bucket capacity (max bucket deg ~1130; 4.5+ sigma margin)

typedef __attribute__((ext_vector_type(8))) short bf16x8;   // 8 bf16 = 4 VGPR (MFMA A/B frag)
typedef __attribute__((ext_vector_type(4))) float f32x4;    // MFMA C/D frag

// fp32 -> bf16 round-to-nearest-even
__device__ __forceinline__ unsigned short f2bf(float f) {
  unsigned x = __float_as_uint(f);
  unsigned r = ((x >> 16) & 1u) + 0x7fffu;
  return (unsigned short)((x + r) >> 16);
}
__device__ __forceinline__ float bf2f(unsigned short u) {
  return __uint_as_float(((unsigned)u) << 16);
}

// ---------------- binning into padded buckets: colp[b*CAP + r] ----------------

__global__ __launch_bounds__(256) void k_bin(const int* __restrict__ src, const int* __restrict__ dst,
                                             int* __restrict__ bcur, int* __restrict__ colp) {
  __shared__ int hist[NBKT];
  __shared__ int gbase[NBKT];
  int t = threadIdx.x;
  for (int b = t; b < NBKT; b += 256) hist[b] = 0;
  __syncthreads();
  int e0 = blockIdx.x * 8192;
#pragma unroll
  for (int i = 0; i < 32; i++) {
    int e = e0 + i * 256 + t;
    if (e < NE) atomicAdd(&hist[dst[e] >> 6], 1);
  }
  __syncthreads();
  for (int b = t; b < NBKT; b += 256) {
    int c = hist[b];
    gbase[b] = c ? atomicAdd(&bcur[b], c) : 0;
    hist[b] = 0;  // reuse as rank counter
  }
  __syncthreads();
#pragma unroll
  for (int i = 0; i < 32; i++) {
    int e = e0 + i * 256 + t;
    if (e < NE) {
      int s = src[e], d = dst[e];
      int b = d >> 6;
      int r = atomicAdd(&hist[b], 1);
      colp[b * CAP + gbase[b] + r] = (s << 6) | (d & 63);
    }
  }
}

// ---------------- bucket-local sort to padded CSR + dinv/rowst/rowen (+ gptr folded) ----------------

__global__ __launch_bounds__(256) void k_csr(const int* __restrict__ bcur, const int* __restrict__ colp,
                                             int* __restrict__ cols, float* __restrict__ dinv,
                                             int* __restrict__ rowst, int* __restrict__ rowen,
                                             const int* __restrict__ batch, int* __restrict__ gptr) {
  __shared__ int hist[64];
  __shared__ int excl[65];
  int t = threadIdx.x;
  int b = blockIdx.x;

  // folded gptr: graph segment pointers from sorted batch (independent work)
  int tid = b * 256 + t;
  if (tid < NN) {
    int bi = batch[tid];
    int bp = (tid > 0) ? batch[tid - 1] : -1;
    for (int g = bp + 1; g <= bi; g++) gptr[g] = tid;
    if (tid == NN - 1) {
      for (int g = bi + 1; g <= NG; g++) gptr[g] = NN;
    }
  }

  int base = b * CAP;
  int cnt = bcur[b];
  if (t < 64) hist[t] = 0;
  __syncthreads();
  for (int e = t; e < cnt; e += 256) atomicAdd(&hist[colp[base + e] & 63], 1);
  __syncthreads();
  if (t == 0) {
    int run = 0;
#pragma unroll
    for (int i = 0; i < 64; i++) { excl[i] = run; run += hist[i]; }
    excl[64] = run;
  }
  __syncthreads();
  if (t < 64) {
    int n = b * 64 + t;
    rowst[n] = base + excl[t];
    rowen[n] = base + excl[t + 1];
    if (n < NN) dinv[n] = rsqrtf((float)(hist[t] + 1));  // +1 self-loop
    hist[t] = 0;  // reuse as cursor
  }
  __syncthreads();
  for (int e = t; e < cnt; e += 256) {
    int w = colp[base + e];
    int d = w & 63;
    int r = atomicAdd(&hist[d], 1);
    cols[base + excl[d] + r] = w >> 6;
  }
}

// ---------------- encoder: X0 = [x|pos] @ enc_W + enc_b ----------------

__global__ __launch_bounds__(256) void k_encoder(const float* __restrict__ x, const float* __restrict__ pos,
                                                 const float* __restrict__ W, const float* __restrict__ b,
                                                 float* __restrict__ X0) {
  __shared__ float Ws[16 * 64];
  __shared__ float bs[64];
  int t = threadIdx.x;
  for (int i = t; i < 1024; i += 256) Ws[i] = W[i];
  if (t < 64) bs[t] = b[t];
  __syncthreads();
  int n = blockIdx.x * 4 + (t >> 6);
  int h = t & 63;
  if (n >= NN) return;
  float acc = bs[h];
#pragma unroll
  for (int f = 0; f < 14; f++) acc += x[n * 14 + f] * Ws[f * 64 + h];
  acc += pos[n * 2 + 0] * Ws[14 * 64 + h];
  acc += pos[n * 2 + 1] * Ws[15 * 64 + h];
  X0[n * 64 + h] = acc;
}

// ---------------- W fragment precompute for MFMA (one-time, 32 KB) ----------------
// Fragment convention (16x16x32 bf16): lane = (idx&15) + 16*kb; element e <-> k = s*32 + kb*8 + e.
// A uses idx = output row (node), B uses idx = output col (h). C/D: col=lane&15, row=(lane>>4)*4+reg.
// fid = mat*16 + part*8 + s*4 + ntile; mat: 0=conv 1=res; part: 0=bf16-hi 1=bf16-lo.
// Wf[fid][lane][e] bf16 -> per-wave frag load = coalesced dwordx4, L2-broadcast across blocks.

__global__ __launch_bounds__(256) void k_wprep(const float* __restrict__ Wc, const float* __restrict__ Wr,
                                               unsigned short* __restrict__ Wf) {
  int t = blockIdx.x * 256 + threadIdx.x;   // 2048 threads = 32 frags * 64 lanes
  if (t >= 2048) return;
  int fid = t >> 6;
  int lane = t & 63;
  int ntile = fid & 3, s = (fid >> 2) & 1, part = (fid >> 3) & 1, mat = fid >> 4;
  const float* W = mat ? Wr : Wc;
  int col = ntile * 16 + (lane & 15);
  int k0 = s * 32 + (lane >> 4) * 8;
#pragma unroll
  for (int e = 0; e < 8; e++) {
    float w = W[(k0 + e) * 64 + col];
    unsigned short h = f2bf(w);
    Wf[(size_t)fid * 512 + lane * 8 + e] = part ? f2bf(w - bf2f(h)) : h;
  }
}

// ---------------- fused dual GEMM + epilogue, MFMA version (LDS-free) ----------------
// mode 0: X = Xin (encoder output). mode 1: X = relu(Xin + dinv[n]*bf2f(gsum[n])).
// Split-bf16: X = xh + xl, W = wh + wl; X@W ~= xh@wh + xh@wl + xl@wh (rel err ~2^-16, fp32 acc).
// hWbf = bf16( dinv[n] * (X @ conv_W) );  agg = X @ res_W + res_b + conv_b + dinv*hv (self-loop fp32).
// 4 waves/block, each wave owns a 16-node m-tile x full 64 cols: 48 MFMA + ~70 VMEM, zero LDS.

__global__ __launch_bounds__(256) void k_gemm_dual(const float* __restrict__ Xin,
                                                   const unsigned short* __restrict__ gsum,
                                                   const unsigned short* __restrict__ Wf,
                                                   const float* __restrict__ cb, const float* __restrict__ rb,
                                                   const float* __restrict__ dinv,
                                                   unsigned short* __restrict__ hWbf, float* __restrict__ agg,
                                                   int mode) {
  int lane = threadIdx.x & 63;
  int wv = threadIdx.x >> 6;
  int col16 = lane & 15;
  int kb = lane >> 4;
  int n0 = blockIdx.x * 64 + wv * 16;

  // ---- A fragments: this lane supplies X row (n0+col16), k = s*32 + kb*8 + e
  int nr = n0 + col16;
  int nc = nr < NN ? nr : NN - 1;   // clamp loads; garbage rows never stored
  const float* xrow = Xin + (size_t)nc * 64;
  float v0[8], v1[8];
  {
    float4 a = *(const float4*)(xrow + kb * 8);
    float4 b = *(const float4*)(xrow + kb * 8 + 4);
    float4 c = *(const float4*)(xrow + 32 + kb * 8);
    float4 d = *(const float4*)(xrow + 32 + kb * 8 + 4);
    v0[0] = a.x; v0[1] = a.y; v0[2] = a.z; v0[3] = a.w;
    v0[4] = b.x; v0[5] = b.y; v0[6] = b.z; v0[7] = b.w;
    v1[0] = c.x; v1[1] = c.y; v1[2] = c.z; v1[3] = c.w;
    v1[4] = d.x; v1[5] = d.y; v1[6] = d.z; v1[7] = d.w;
  }
  if (mode) {
    float dvn = dinv[nc];
    const unsigned* grow = (const unsigned*)(gsum + (size_t)nc * 64);
    uint4 g0 = *(const uint4*)(grow + kb * 4);
    uint4 g1 = *(const uint4*)(grow + 16 + kb * 4);
    unsigned ga[4] = {g0.x, g0.y, g0.z, g0.w};
    unsigned gb[4] = {g1.x, g1.y, g1.z, g1.w};
#pragma unroll
    for (int e = 0; e < 4; e++) {
      v0[2 * e]     = fmaxf(v0[2 * e]     + dvn * bf2f((unsigned short)(ga[e] & 0xffff)), 0.f);
      v0[2 * e + 1] = fmaxf(v0[2 * e + 1] + dvn * bf2f((unsigned short)(ga[e] >> 16)), 0.f);
      v1[2 * e]     = fmaxf(v1[2 * e]     + dvn * bf2f((unsigned short)(gb[e] & 0xffff)), 0.f);
      v1[2 * e + 1] = fmaxf(v1[2 * e + 1] + dvn * bf2f((unsigned short)(gb[e] >> 16)), 0.f);
    }
  }
  bf16x8 ah0, al0, ah1, al1;
#pragma unroll
  for (int e = 0; e < 8; e++) {
    unsigned short h0 = f2bf(v0[e]);
    ah0[e] = (short)h0;
    al0[e] = (short)f2bf(v0[e] - bf2f(h0));
    unsigned short h1 = f2bf(v1[e]);
    ah1[e] = (short)h1;
    al1[e] = (short)f2bf(v1[e] - bf2f(h1));
  }

  // ---- MFMA: 4 n-tiles x (2 k-steps x 3 split-terms) x 2 matrices = 48 MFMA
  f32x4 aC[4] = {{0.f, 0.f, 0.f, 0.f}, {0.f, 0.f, 0.f, 0.f}, {0.f, 0.f, 0.f, 0.f}, {0.f, 0.f, 0.f, 0.f}};
  f32x4 aR[4] = {{0.f, 0.f, 0.f, 0.f}, {0.f, 0.f, 0.f, 0.f}, {0.f, 0.f, 0.f, 0.f}, {0.f, 0.f, 0.f, 0.f}};
  const bf16x8* WFv = (const bf16x8*)Wf;
#pragma unroll
  for (int j = 0; j < 4; j++) {
    bf16x8 wch0 = WFv[(j)      * 64 + lane];
    bf16x8 wch1 = WFv[(4 + j)  * 64 + lane];
    bf16x8 wcl0 = WFv[(8 + j)  * 64 + lane];
    bf16x8 wcl1 = WFv[(12 + j) * 64 + lane];
    bf16x8 wrh0 = WFv[(16 + j) * 64 + lane];
    bf16x8 wrh1 = WFv[(20 + j) * 64 + lane];
    bf16x8 wrl0 = WFv[(24 + j) * 64 + lane];
    bf16x8 wrl1 = WFv[(28 + j) * 64 + lane];
    f32x4 c = aC[j];
    c = __builtin_amdgcn_mfma_f32_16x16x32_bf16(ah0, wch0, c, 0, 0, 0);
    c = __builtin_amdgcn_mfma_f32_16x16x32_bf16(ah1, wch1, c, 0, 0, 0);
    c = __builtin_amdgcn_mfma_f32_16x16x32_bf16(al0, wch0, c, 0, 0, 0);
    c = __builtin_amdgcn_mfma_f32_16x16x32_bf16(al1, wch1, c, 0, 0, 0);
    c = __builtin_amdgcn_mfma_f32_16x16x32_bf16(ah0, wcl0, c, 0, 0, 0);
    c = __builtin_amdgcn_mfma_f32_16x16x32_bf16(ah1, wcl1, c, 0, 0, 0);
    aC[j] = c;
    f32x4 r = aR[j];
    r = __builtin_amdgcn_mfma_f32_16x16x32_bf16(ah0, wrh0, r, 0, 0, 0);
    r = __builtin_amdgcn_mfma_f32_16x16x32_bf16(ah1, wrh1, r, 0, 0, 0);
    r = __builtin_amdgcn_mfma_f32_16x16x32_bf16(al0, wrh0, r, 0, 0, 0);
    r = __builtin_amdgcn_mfma_f32_16x16x32_bf16(al1, wrh1, r, 0, 0, 0);
    r = __builtin_amdgcn_mfma_f32_16x16x32_bf16(ah0, wrl0, r, 0, 0, 0);
    r = __builtin_amdgcn_mfma_f32_16x16x32_bf16(ah1, wrl1, r, 0, 0, 0);
    aR[j] = r;
  }

  // ---- epilogue: D layout col=lane&15, row=(lane>>4)*4+reg
  float cbv[4], rbv[4];
#pragma unroll
  for (int j = 0; j < 4; j++) { cbv[j] = cb[j * 16 + col16]; rbv[j] = rb[j * 16 + col16]; }
  int rbase = kb * 4;
#pragma unroll
  for (int r = 0; r < 4; r++) {
    int node = n0 + rbase + r;
    if (node < NN) {
      float dv = dinv[node];
      size_t o = (size_t)node * 64 + col16;
#pragma unroll
      for (int j = 0; j < 4; j++) {
        float hc = dv * aC[j][r];
        unsigned short hb = f2bf(hc);
        hWbf[o + j * 16] = hb;
        agg[o + j * 16] = aR[j][r] + rbv[j] + cbv[j] + dv * hc;
      }
    }
  }
}

// ---------------- CSR gather, PAIRED rows: 2 edges per load instruction ----------------
// One 64-lane wave per dst node. Lane = (p = lane>>5, h2 = lane&31): handles h = 2*h2,
// 2*h2+1 of edge-slot pair-member p. A bf16 row is 128 B = 32 lanes x 4 B, so one wave
// load covers TWO rows -> 8 load instructions per 16 edges.
// End: combine p-halves via shfl, lanes 0..31 hold the full 64-h sum as pairs.
// Last layer reads agg once and fuses decode.

__global__ __launch_bounds__(256) void k_gather(const int* __restrict__ rowst, const int* __restrict__ rowen,
                                                const int* __restrict__ cols,
                                                const unsigned short* __restrict__ hWbf,
                                                unsigned short* __restrict__ gsum,
                                                const float* __restrict__ agg, const float* __restrict__ dinv,
                                                const float* __restrict__ decW, float* __restrict__ Xo,
                                                int last) {
  int lane = threadIdx.x & 63;
  int h2 = lane & 31;   // h-pair: h = 2*h2, 2*h2+1
  int p = lane >> 5;    // which member of each edge pair
  int n = __builtin_amdgcn_readfirstlane(blockIdx.x * 4 + (threadIdx.x >> 6));
  int st = rowst[n];
  int en = rowen[n];
  int deg = en - st;
  float a0 = 0.f, a1 = 0.f;
  for (int base = 0; base < deg; base += 64) {
    int cnt = deg - base;
    if (cnt > 64) cnt = 64;
    int li = lane < cnt ? lane : cnt - 1;
    int colv = cols[st + base + li];  // one coalesced load of up to 64 indices
    for (int j = 0; j < cnt; j += 16) {
      int e0 = j + 0 + p, e1 = j + 2 + p, e2 = j + 4 + p, e3 = j + 6 + p;
      int e4 = j + 8 + p, e5 = j + 10 + p, e6 = j + 12 + p, e7 = j + 14 + p;
      int s0 = __shfl(colv, e0 < cnt ? e0 : j, 64);
      int s1 = __shfl(colv, e1 < cnt ? e1 : j, 64);
      int s2 = __shfl(colv, e2 < cnt ? e2 : j, 64);
      int s3 = __shfl(colv, e3 < cnt ? e3 : j, 64);
      int s4 = __shfl(colv, e4 < cnt ? e4 : j, 64);
      int s5 = __shfl(colv, e5 < cnt ? e5 : j, 64);
      int s6 = __shfl(colv, e6 < cnt ? e6 : j, 64);
      int s7 = __shfl(colv, e7 < cnt ? e7 : j, 64);
      unsigned u0 = *(const unsigned*)(hWbf + (size_t)s0 * 64 + h2 * 2);
      unsigned u1 = *(const unsigned*)(hWbf + (size_t)s1 * 64 + h2 * 2);
      unsigned u2 = *(const unsigned*)(hWbf + (size_t)s2 * 64 + h2 * 2);
      unsigned u3 = *(const unsigned*)(hWbf + (size_t)s3 * 64 + h2 * 2);
      unsigned u4 = *(const unsigned*)(hWbf + (size_t)s4 * 64 + h2 * 2);
      unsigned u5 = *(const unsigned*)(hWbf + (size_t)s5 * 64 + h2 * 2);
      unsigned u6 = *(const unsigned*)(hWbf + (size_t)s6 * 64 + h2 * 2);
      unsigned u7 = *(const unsigned*)(hWbf + (size_t)s7 * 64 + h2 * 2);
      a0 += (e0 < cnt) ? bf2f((unsigned short)(u0 & 0xffff)) : 0.f;
      a1 += (e0 < cnt) ? bf2f((unsigned short)(u0 >> 16)) : 0.f;
      a0 += (e1 < cnt) ? bf2f((unsigned short)(u1 & 0xffff)) : 0.f;
      a1 += (e1 < cnt) ? bf2f((unsigned short)(u1 >> 16)) : 0.f;
      a0 += (e2 < cnt) ? bf2f((unsigned short)(u2 & 0xffff)) : 0.f;
      a1 += (e2 < cnt) ? bf2f((unsigned short)(u2 >> 16)) : 0.f;
      a0 += (e3 < cnt) ? bf2f((unsigned short)(u3 & 0xffff)) : 0.f;
      a1 += (e3 < cnt) ? bf2f((unsigned short)(u3 >> 16)) : 0.f;
      a0 += (e4 < cnt) ? bf2f((unsigned short)(u4 & 0xffff)) : 0.f;
      a1 += (e4 < cnt) ? bf2f((unsigned short)(u4 >> 16)) : 0.f;
      a0 += (e5 < cnt) ? bf2f((unsigned short)(u5 & 0xffff)) : 0.f;
      a1 += (e5 < cnt) ? bf2f((unsigned short)(u5 >> 16)) : 0.f;
      a0 += (e6 < cnt) ? bf2f((unsigned short)(u6 & 0xffff)) : 0.f;
      a1 += (e6 < cnt) ? bf2f((unsigned short)(u6 >> 16)) : 0.f;
      a0 += (e7 < cnt) ? bf2f((unsigned short)(u7 & 0xffff)) : 0.f;
      a1 += (e7 < cnt) ? bf2f((unsigned short)(u7 >> 16)) : 0.f;
    }
  }
  // combine the two pair-halves: lanes 0..31 get full sums for their h-pair
  a0 += __shfl_down(a0, 32, 64);
  a1 += __shfl_down(a1, 32, 64);
  if (!last) {
    if (lane < 32) {
      unsigned outw = (unsigned)f2bf(a0) | ((unsigned)f2bf(a1) << 16);
      *(unsigned*)(gsum + (size_t)n * 64 + h2 * 2) = outw;
    }
  } else {
    float dv = dinv[n];
    float2 ag = *(const float2*)(agg + (size_t)n * 64 + h2 * 2);  // valid addr for all lanes
    float xf0 = ag.x + dv * a0;
    float xf1 = ag.y + dv * a1;
    float v = fmaxf(xf0, 0.f) * decW[h2 * 2] + fmaxf(xf1, 0.f) * decW[h2 * 2 + 1];
    v = (lane < 32) ? v : 0.f;  // upper half holds stale partials -> zero them
#pragma unroll
    for (int off = 32; off > 0; off >>= 1) v += __shfl_down(v, off, 64);
    if (lane == 0) Xo[n] = v;
  }
}

// ---------------- graph pooling: out[g] = sum Xo[gptr[g]:gptr[g+1]] + cnt*decb ----------------

__global__ __launch_bounds__(256) void k_pool(const float* __restrict__ Xo, const int* __restrict__ gptr,
                                              const float* __restrict__ decb, float* __restrict__ out) {
  __shared__ float part[4];
  int g = blockIdx.x;
  int t = threadIdx.x;
  int st = gptr[g], en = gptr[g + 1];
  float v = 0.f;
  for (int i = st + t; i < en; i += 256) v += Xo[i];
#pragma unroll
  for (int off = 32; off > 0; off >>= 1) v += __shfl_down(v, off, 64);
  if ((t & 63) == 0) part[t >> 6] = v;
  __syncthreads();
  if (t == 0) out[g] = part[0] + part[1] + part[2] + part[3] + (float)(en - st) * decb[0];
}

// ---------------- launch ----------------

extern "C" void kernel_launch(void* const* d_in, const int* in_sizes, int n_in,
                              void* d_out, int out_size, void* d_ws, size_t ws_size,
                              hipStream_t stream) {
  (void)in_sizes; (void)n_in; (void)out_size; (void)ws_size;
  const float* x     = (const float*)d_in[0];
  const float* pos   = (const float*)d_in[1];
  const int*   ei    = (const int*)d_in[2];
  const int*   batch = (const int*)d_in[3];
  const float* encW  = (const float*)d_in[4];
  const float* encb  = (const float*)d_in[5];
  const float* convW = (const float*)d_in[6];
  const float* convb = (const float*)d_in[7];
  const float* resW  = (const float*)d_in[8];
  const float* resb  = (const float*)d_in[9];
  const float* decW  = (const float*)d_in[10];
  const float* decb  = (const float*)d_in[11];
  float* out = (float*)d_out;

  const int* src = ei;       // edge_index[0]
  const int* dst = ei + NE;  // edge_index[1]

  // workspace layout (4-byte elems)
  float*          ws     = (float*)d_ws;
  float*          dinv   = ws;                          // [NPAD]
  int*            rowst  = (int*)(ws + NPAD);           // [NPAD]
  int*            rowen  = (int*)(ws + 2 * NPAD);       // [NPAD]
  int*            bcur   = (int*)(ws + 3 * NPAD);       // [1024]
  int*            gptr   = bcur + 1024;                 // [NG+1]
  float*          Xo     = (float*)(gptr + 512);        // [NPAD]
  int*            colp   = (int*)(Xo + NPAD);           // [NBKT*CAP] packed (src<<6)|dstLow
  int*            cols   = colp + NBKT * CAP;           // [NBKT*CAP] sorted src
  unsigned short* hWbf   = (unsigned short*)(cols + NBKT * CAP);        // [NPAD*64] bf16
  unsigned short* gsum   = hWbf + (size_t)NPAD * 64;                    // [NPAD*64] bf16
  float*          bufA   = (float*)(gsum + (size_t)NPAD * 64);          // [NN*NH]
  float*          bufB   = bufA + NN * NH;                              // [NN*NH]
  unsigned short* Wf     = (unsigned short*)(bufB + NN * NH);           // [32*512] bf16 frag W

  hipMemsetAsync(bcur, 0, 1024 * sizeof(int), stream);

  k_wprep<<<8, 256, 0, stream>>>(convW, resW, Wf);
  k_bin<<<(NE + 8191) / 8192, 256, 0, stream>>>(src, dst, bcur, colp);
  k_csr<<<NBKT, 256, 0, stream>>>(bcur, colp, cols, dinv, rowst, rowen, batch, gptr);

  k_encoder<<<(NN + 3) / 4, 256, 0, stream>>>(x, pos, encW, encb, bufA);

  float* aggIn = bufA;   // X0 for l=0; thereafter agg_{l-1}
  float* aggOut = bufB;
  for (int l = 0; l < 5; l++) {
    int last = (l == 4) ? 1 : 0;
    k_gemm_dual<<<NBKT, 256, 0, stream>>>(aggIn, gsum, Wf, convb, resb, dinv,
                                          hWbf, aggOut, l > 0 ? 1 : 0);
    k_gather<<<NN / 4, 256, 0, stream>>>(rowst, rowen, cols, hWbf, gsum,
                                         aggOut, dinv, decW, Xo, last);
    float* tmp = aggIn; aggIn = aggOut; aggOut = tmp;
  }
  k_pool<<<NG, 256, 0, stream>>>(Xo, gptr, decb, out);
}